// Round 2
// baseline (700.169 us; speedup 1.0000x reference)
//
#include <hip/hip_runtime.h>

// get_fc_pix_discriminator_1x1_solo: fused 5-layer per-pixel MLP + BCE mean.
// B=4, C=19, H=256, W=512 -> 524288 pixels. dims 19->64->128->256->512->1.
// R1: fuse L4+L5+BCE in registers (no h4 LDS buffer) -> LDS 98KB -> ~50KB,
// 1 -> 3 WGs/CU. launch_bounds(256,3) to keep VGPRs <= ~170.

#define HW_ 131072      // 256*512 = 2^17
#define NPIX 524288

using bf16x8 = __attribute__((ext_vector_type(8))) short;
using f32x4  = __attribute__((ext_vector_type(4))) float;

__device__ __forceinline__ unsigned short f2bf(float f) {
  unsigned u = __builtin_bit_cast(unsigned, f);
  u += 0x7FFFu + ((u >> 16) & 1u);   // round-to-nearest-even
  return (unsigned short)(u >> 16);
}

// ---- weight bf16 pre-conversion ------------------------------------------
// layout in ws (elements): W1p [64][32] @0 (k>=19 zero), W2 [128][64] @2048,
// W3 [256][128] @10240, W4 [512][256] @43008. total 174080 bf16.
#define OW1 0
#define OW2 2048
#define OW3 10240
#define OW4 43008
#define WTOT 174080

__global__ void wconv_kernel(const float* __restrict__ W1, const float* __restrict__ W2,
                             const float* __restrict__ W3, const float* __restrict__ W4,
                             unsigned short* __restrict__ wb) {
  int i = blockIdx.x * 256 + threadIdx.x;
  if (i < 2048) {
    int o = i >> 5, k = i & 31;
    wb[i] = f2bf(k < 19 ? W1[o * 19 + k] : 0.f);
  } else if (i < 10240) {
    wb[i] = f2bf(W2[i - 2048]);
  } else if (i < 43008) {
    wb[i] = f2bf(W3[i - 10240]);
  } else if (i < WTOT) {
    wb[i] = f2bf(W4[i - 43008]);
  }
}

// ---- one MFMA layer: out[p][o] = leaky(bias[o] + sum_c in[p][c]*W[o][c]) ---
// in/out are LDS bf16 tiles [64 px][K or N], XOR-swizzled in 16B granules:
//   addr = px*S + (g ^ (px&MASK))*16 + (byte&15),  MASK = min(S/16,8)-1
// A-frag (16x16x32): lane l: row=l&15, k=8*(l>>4)+j  (16B contiguous)
// B-frag:            lane l: col=l&15, k=8*(l>>4)+j  (16B from W row col)
// D:                 lane l: col=l&15, row=4*(l>>4)+r
template <int K0, int KP, int N, bool PRE>
__device__ __forceinline__ void layer_mfma(const unsigned short* __restrict__ Wb,
                                           const float* __restrict__ Wf,
                                           const float* __restrict__ bias,
                                           const unsigned char* __restrict__ in,
                                           unsigned char* __restrict__ out,
                                           int wave, int lane) {
  constexpr int KS = KP / 32;
  constexpr int SIN = KP * 2;
  constexpr int SOUT = N * 2;
  constexpr int MIN_ = (SIN / 16 < 8 ? SIN / 16 : 8) - 1;
  constexpr int MOUT = (SOUT / 16 < 8 ? SOUT / 16 : 8) - 1;
  constexpr int NB = N / 64;  // colblocks per wave (waves split N 4-way)

  bf16x8 a[4][KS];
#pragma unroll
  for (int rb = 0; rb < 4; rb++) {
#pragma unroll
    for (int ks = 0; ks < KS; ks++) {
      int px = rb * 16 + (lane & 15);
      int kb = ks * 64 + ((lane >> 4) << 4);
      int g = (kb >> 4) ^ (px & MIN_);
      a[rb][ks] = *(const bf16x8*)(in + px * SIN + (g << 4));
    }
  }

#pragma unroll
  for (int nb = 0; nb < NB; nb++) {
    int col = (wave * NB + nb) * 16 + (lane & 15);
    f32x4 acc[4];
#pragma unroll
    for (int rb = 0; rb < 4; rb++) acc[rb] = f32x4{0.f, 0.f, 0.f, 0.f};
#pragma unroll
    for (int ks = 0; ks < KS; ks++) {
      bf16x8 bfrag;
      int kbase = ks * 32 + ((lane >> 4) << 3);
      if constexpr (PRE) {
        bfrag = *(const bf16x8*)(Wb + col * KP + kbase);
      } else {
#pragma unroll
        for (int j = 0; j < 8; j++) {
          int kk = kbase + j;
          float v = (K0 == KP || kk < K0) ? Wf[col * K0 + kk] : 0.f;
          bfrag[j] = (short)f2bf(v);
        }
      }
#pragma unroll
      for (int rb = 0; rb < 4; rb++)
        acc[rb] = __builtin_amdgcn_mfma_f32_16x16x32_bf16(a[rb][ks], bfrag, acc[rb], 0, 0, 0);
    }
    float bv = bias[col];
#pragma unroll
    for (int rb = 0; rb < 4; rb++) {
#pragma unroll
      for (int r = 0; r < 4; r++) {
        float v = acc[rb][r] + bv;
        v = v >= 0.f ? v : 0.2f * v;  // LeakyReLU(0.2)
        int px = rb * 16 + ((lane >> 4) << 2) + r;
        int cb = col * 2;
        int g = (cb >> 4) ^ (px & MOUT);
        *(unsigned short*)(out + px * SOUT + (g << 4) + (cb & 15)) = f2bf(v);
      }
    }
  }
}

// ---- fused layer4 + layer5 + z-partials (no LDS h4) -----------------------
// in: h3 [64][256] bf16 swizzled. Each wave covers 128 cols of the 512.
// After MFMA+bias+leaky, multiply by W5[col] and accumulate per-lane partial
// z; butterfly-reduce over the 16-lane col group; stash per-wave partials.
template <bool PRE>
__device__ __forceinline__ void layer4_fused(const unsigned short* __restrict__ Wb,
                                             const float* __restrict__ Wf,
                                             const float* __restrict__ b4,
                                             const float* __restrict__ W5f,
                                             const unsigned char* __restrict__ in,
                                             float* __restrict__ zpartial,  // [4][64]
                                             int wave, int lane) {
  constexpr int KP = 256, KS = 8, SIN = 512, MIN_ = 7, NB = 8;

  bf16x8 a[4][KS];
#pragma unroll
  for (int rb = 0; rb < 4; rb++) {
#pragma unroll
    for (int ks = 0; ks < KS; ks++) {
      int px = rb * 16 + (lane & 15);
      int kb = ks * 64 + ((lane >> 4) << 4);
      int g = (kb >> 4) ^ (px & MIN_);
      a[rb][ks] = *(const bf16x8*)(in + px * SIN + (g << 4));
    }
  }

  float zp[4][4];
#pragma unroll
  for (int rb = 0; rb < 4; rb++)
#pragma unroll
    for (int r = 0; r < 4; r++) zp[rb][r] = 0.f;

#pragma unroll
  for (int nb = 0; nb < NB; nb++) {
    int col = (wave * NB + nb) * 16 + (lane & 15);
    f32x4 acc[4];
#pragma unroll
    for (int rb = 0; rb < 4; rb++) acc[rb] = f32x4{0.f, 0.f, 0.f, 0.f};
#pragma unroll
    for (int ks = 0; ks < KS; ks++) {
      bf16x8 bfrag;
      int kbase = ks * 32 + ((lane >> 4) << 3);
      if constexpr (PRE) {
        bfrag = *(const bf16x8*)(Wb + col * KP + kbase);
      } else {
#pragma unroll
        for (int j = 0; j < 8; j++) {
          float v = Wf[col * KP + kbase + j];
          bfrag[j] = (short)f2bf(v);
        }
      }
#pragma unroll
      for (int rb = 0; rb < 4; rb++)
        acc[rb] = __builtin_amdgcn_mfma_f32_16x16x32_bf16(a[rb][ks], bfrag, acc[rb], 0, 0, 0);
    }
    float bv = b4[col];
    float w5 = W5f[col];
#pragma unroll
    for (int rb = 0; rb < 4; rb++) {
#pragma unroll
      for (int r = 0; r < 4; r++) {
        float v = acc[rb][r] + bv;
        v = v >= 0.f ? v : 0.2f * v;  // LeakyReLU(0.2)
        zp[rb][r] += v * w5;
      }
    }
  }

  // butterfly-reduce across the 16 lanes sharing (lane>>4): sums over cols
#pragma unroll
  for (int m = 1; m <= 8; m <<= 1) {
#pragma unroll
    for (int rb = 0; rb < 4; rb++)
#pragma unroll
      for (int r = 0; r < 4; r++) zp[rb][r] += __shfl_xor(zp[rb][r], m);
  }
  if ((lane & 15) == 0) {
    int g4 = lane >> 4;
#pragma unroll
    for (int rb = 0; rb < 4; rb++)
#pragma unroll
      for (int r = 0; r < 4; r++)
        zpartial[wave * 64 + rb * 16 + g4 * 4 + r] = zp[rb][r];
  }
}

template <bool PRE>
__global__ __launch_bounds__(256, 3) void disc_main(
    const float* __restrict__ x, const float* __restrict__ lbl,
    const unsigned short* __restrict__ wb,
    const float* __restrict__ W1f, const float* __restrict__ b1,
    const float* __restrict__ W2f, const float* __restrict__ b2,
    const float* __restrict__ W3f, const float* __restrict__ b3,
    const float* __restrict__ W4f, const float* __restrict__ b4,
    const float* __restrict__ W5f, const float* __restrict__ b5,
    float* __restrict__ out) {
  __shared__ __align__(16) unsigned char bufA[16 * 1024];  // x(4K), h2(16K)
  __shared__ __align__(16) unsigned char bufB[32 * 1024];  // h1(8K), h3(32K)
  __shared__ float zpartial[4 * 64];

  int t = threadIdx.x;
  int wave = t >> 6, lane = t & 63;
  long n0 = (long)blockIdx.x * 64;
  int b = (int)(n0 >> 17);
  int hw0 = (int)(n0 & (HW_ - 1));

  // zero the 4KB x-staging region (covers the k-padding 19->32)
  ((uint4*)bufA)[t] = uint4{0, 0, 0, 0};
  __syncthreads();
  // stage x tile -> bufA as [64 px][32] bf16, swizzle MASK=3
  {
    int px = t & 63;
    for (int c = t >> 6; c < 19; c += 4) {
      float v = x[(((long)b * 19 + c) << 17) + hw0 + px];
      int cb = c * 2;
      int g = (cb >> 4) ^ (px & 3);
      *(unsigned short*)(bufA + px * 64 + (g << 4) + (cb & 15)) = f2bf(v);
    }
  }
  __syncthreads();

  layer_mfma<19, 32, 64, PRE>(wb + OW1, W1f, b1, bufA, bufB, wave, lane);
  __syncthreads();
  layer_mfma<64, 64, 128, PRE>(wb + OW2, W2f, b2, bufB, bufA, wave, lane);
  __syncthreads();
  layer_mfma<128, 128, 256, PRE>(wb + OW3, W3f, b3, bufA, bufB, wave, lane);
  __syncthreads();
  layer4_fused<PRE>(wb + OW4, W4f, b4, W5f, bufB, zpartial, wave, lane);
  __syncthreads();

  // wave 0: combine the 4 wave-partials per pixel, BCE, block reduce
  if (t < 64) {
    float z = zpartial[t] + zpartial[64 + t] + zpartial[128 + t] +
              zpartial[192 + t] + b5[0];
    float l = lbl[n0 + t];
    float w = fmaxf(z, 0.f) - z * l + log1pf(expf(-fabsf(z)));
#pragma unroll
    for (int m = 1; m <= 32; m <<= 1) w += __shfl_xor(w, m);
    if (t == 0) atomicAdd(out, w * (1.f / (float)NPIX));
  }
}

extern "C" void kernel_launch(void* const* d_in, const int* in_sizes, int n_in,
                              void* d_out, int out_size, void* d_ws, size_t ws_size,
                              hipStream_t stream) {
  const float* x   = (const float*)d_in[0];
  const float* lbl = (const float*)d_in[1];
  const float* W1  = (const float*)d_in[2];
  const float* b1  = (const float*)d_in[3];
  const float* W2  = (const float*)d_in[4];
  const float* b2  = (const float*)d_in[5];
  const float* W3  = (const float*)d_in[6];
  const float* b3  = (const float*)d_in[7];
  const float* W4  = (const float*)d_in[8];
  const float* b4  = (const float*)d_in[9];
  const float* W5  = (const float*)d_in[10];
  const float* b5  = (const float*)d_in[11];
  float* out = (float*)d_out;

  hipMemsetAsync(d_out, 0, sizeof(float), stream);

  bool pre = ws_size >= (size_t)WTOT * sizeof(unsigned short);
  if (pre) {
    unsigned short* wbp = (unsigned short*)d_ws;
    wconv_kernel<<<(WTOT + 255) / 256, 256, 0, stream>>>(W1, W2, W3, W4, wbp);
    disc_main<true><<<NPIX / 64, 256, 0, stream>>>(x, lbl, wbp, W1, b1, W2, b2, W3, b3,
                                                   W4, b4, W5, b5, out);
  } else {
    disc_main<false><<<NPIX / 64, 256, 0, stream>>>(x, lbl, nullptr, W1, b1, W2, b2, W3,
                                                    b3, W4, b4, W5, b5, out);
  }
}

// Round 3
// 262.564 us; speedup vs baseline: 2.6667x; 2.6667x over previous
//
#include <hip/hip_runtime.h>

// get_fc_pix_discriminator_1x1_solo: fused 5-layer per-pixel MLP + BCE mean.
// B=4, C=19, H=256, W=512 -> 524288 pixels. dims 19->64->128->256->512->1.
// R3: (a) launch_bounds(256,2) -- R2's (256,3) capped VGPRs at 84 and spilled
// 2.7GB to scratch; L4+L5 fusion needs ~200 regs. (b) weights pre-swizzled to
// MFMA-fragment order so every B-load is a fully-coalesced 1KB dwordx4.

#define HW_ 131072      // 256*512 = 2^17
#define NPIX 524288

using bf16x8 = __attribute__((ext_vector_type(8))) short;
using f32x4  = __attribute__((ext_vector_type(4))) float;

__device__ __forceinline__ unsigned short f2bf(float f) {
  unsigned u = __builtin_bit_cast(unsigned, f);
  u += 0x7FFFu + ((u >> 16) & 1u);   // round-to-nearest-even
  return (unsigned short)(u >> 16);
}

// ---- weight bf16 pre-conversion into MFMA-fragment order -------------------
// For a layer (K0 real, KP padded, N cols): fragment space is
//   [cb = col-block 0..N/16) ][ ks = 0..KP/32 ) ][ lane 0..64 ) ][ j 0..8 )
//   col = cb*16 + (lane&15),  k = ks*32 + (lane>>4)*8 + j   (k>=K0 -> 0)
// element offset = ((cb*KS + ks)*64 + lane)*8. A wave's B-frag load is then
// 64 lanes x 16B contiguous.
#define OW1 0
#define OW2 2048
#define OW3 10240
#define OW4 43008
#define WTOT 174080

template <int K0, int KP, int N>
__device__ __forceinline__ void conv_layer(const float* __restrict__ W,
                                           unsigned short* __restrict__ out,
                                           int i) {
  constexpr int KS = KP / 32;
  int frag = i >> 9;
  int cb = frag / KS, ks = frag - cb * KS;
  int r = i & 511;
  int lane = r >> 3, j = r & 7;
  int col = cb * 16 + (lane & 15);
  int k = ks * 32 + ((lane >> 4) << 3) + j;
  out[i] = f2bf(k < K0 ? W[col * K0 + k] : 0.f);
}

__global__ void wconv_kernel(const float* __restrict__ W1, const float* __restrict__ W2,
                             const float* __restrict__ W3, const float* __restrict__ W4,
                             unsigned short* __restrict__ wb) {
  int i = blockIdx.x * 256 + threadIdx.x;
  if (i < OW2) {
    conv_layer<19, 32, 64>(W1, wb + OW1, i - OW1);
  } else if (i < OW3) {
    conv_layer<64, 64, 128>(W2, wb + OW2, i - OW2);
  } else if (i < OW4) {
    conv_layer<128, 128, 256>(W3, wb + OW3, i - OW3);
  } else if (i < WTOT) {
    conv_layer<256, 256, 512>(W4, wb + OW4, i - OW4);
  }
}

// ---- one MFMA layer: out[p][o] = leaky(bias[o] + sum_c in[p][c]*W[o][c]) ---
// in/out are LDS bf16 tiles [64 px][K or N], XOR-swizzled in 16B granules:
//   addr = px*S + (g ^ (px&MASK))*16 + (byte&15),  MASK = min(S/16,8)-1
// A-frag (16x16x32): lane l: row=l&15, k=8*(l>>4)+j
// D:                 lane l: col=l&15, row=4*(l>>4)+r
template <int K0, int KP, int N, bool PRE>
__device__ __forceinline__ void layer_mfma(const unsigned short* __restrict__ Wb,
                                           const float* __restrict__ Wf,
                                           const float* __restrict__ bias,
                                           const unsigned char* __restrict__ in,
                                           unsigned char* __restrict__ out,
                                           int wave, int lane) {
  constexpr int KS = KP / 32;
  constexpr int SIN = KP * 2;
  constexpr int SOUT = N * 2;
  constexpr int MIN_ = (SIN / 16 < 8 ? SIN / 16 : 8) - 1;
  constexpr int MOUT = (SOUT / 16 < 8 ? SOUT / 16 : 8) - 1;
  constexpr int NB = N / 64;  // colblocks per wave (waves split N 4-way)

  bf16x8 a[4][KS];
#pragma unroll
  for (int rb = 0; rb < 4; rb++) {
#pragma unroll
    for (int ks = 0; ks < KS; ks++) {
      int px = rb * 16 + (lane & 15);
      int kb = ks * 64 + ((lane >> 4) << 4);
      int g = (kb >> 4) ^ (px & MIN_);
      a[rb][ks] = *(const bf16x8*)(in + px * SIN + (g << 4));
    }
  }

  // wave-local fragment base: cb = wave*NB + nb
  const unsigned short* wlw = Wb + (((wave * NB) * KS) << 9) + (lane << 3);

#pragma unroll
  for (int nb = 0; nb < NB; nb++) {
    int col = (wave * NB + nb) * 16 + (lane & 15);
    f32x4 acc[4];
#pragma unroll
    for (int rb = 0; rb < 4; rb++) acc[rb] = f32x4{0.f, 0.f, 0.f, 0.f};
#pragma unroll
    for (int ks = 0; ks < KS; ks++) {
      bf16x8 bfrag;
      if constexpr (PRE) {
        bfrag = *(const bf16x8*)(wlw + (((nb * KS + ks)) << 9));
      } else {
        int kbase = ks * 32 + ((lane >> 4) << 3);
#pragma unroll
        for (int j = 0; j < 8; j++) {
          int kk = kbase + j;
          float v = (K0 == KP || kk < K0) ? Wf[col * K0 + kk] : 0.f;
          bfrag[j] = (short)f2bf(v);
        }
      }
#pragma unroll
      for (int rb = 0; rb < 4; rb++)
        acc[rb] = __builtin_amdgcn_mfma_f32_16x16x32_bf16(a[rb][ks], bfrag, acc[rb], 0, 0, 0);
    }
    float bv = bias[col];
#pragma unroll
    for (int rb = 0; rb < 4; rb++) {
#pragma unroll
      for (int r = 0; r < 4; r++) {
        float v = acc[rb][r] + bv;
        v = v >= 0.f ? v : 0.2f * v;  // LeakyReLU(0.2)
        int px = rb * 16 + ((lane >> 4) << 2) + r;
        int cb2 = col * 2;
        int g = (cb2 >> 4) ^ (px & MOUT);
        *(unsigned short*)(out + px * SOUT + (g << 4) + (cb2 & 15)) = f2bf(v);
      }
    }
  }
}

// ---- fused layer4 + layer5 + z-partials (no LDS h4) -----------------------
template <bool PRE>
__device__ __forceinline__ void layer4_fused(const unsigned short* __restrict__ Wb,
                                             const float* __restrict__ Wf,
                                             const float* __restrict__ b4,
                                             const float* __restrict__ W5f,
                                             const unsigned char* __restrict__ in,
                                             float* __restrict__ zpartial,  // [4][64]
                                             int wave, int lane) {
  constexpr int KP = 256, KS = 8, SIN = 512, MIN_ = 7, NB = 8;

  bf16x8 a[4][KS];
#pragma unroll
  for (int rb = 0; rb < 4; rb++) {
#pragma unroll
    for (int ks = 0; ks < KS; ks++) {
      int px = rb * 16 + (lane & 15);
      int kb = ks * 64 + ((lane >> 4) << 4);
      int g = (kb >> 4) ^ (px & MIN_);
      a[rb][ks] = *(const bf16x8*)(in + px * SIN + (g << 4));
    }
  }

  float zp[4][4];
#pragma unroll
  for (int rb = 0; rb < 4; rb++)
#pragma unroll
    for (int r = 0; r < 4; r++) zp[rb][r] = 0.f;

  const unsigned short* wlw = Wb + (((wave * NB) * KS) << 9) + (lane << 3);

#pragma unroll
  for (int nb = 0; nb < NB; nb++) {
    int col = (wave * NB + nb) * 16 + (lane & 15);
    f32x4 acc[4];
#pragma unroll
    for (int rb = 0; rb < 4; rb++) acc[rb] = f32x4{0.f, 0.f, 0.f, 0.f};
#pragma unroll
    for (int ks = 0; ks < KS; ks++) {
      bf16x8 bfrag;
      if constexpr (PRE) {
        bfrag = *(const bf16x8*)(wlw + (((nb * KS + ks)) << 9));
      } else {
        int kbase = ks * 32 + ((lane >> 4) << 3);
#pragma unroll
        for (int j = 0; j < 8; j++) {
          float v = Wf[col * KP + kbase + j];
          bfrag[j] = (short)f2bf(v);
        }
      }
#pragma unroll
      for (int rb = 0; rb < 4; rb++)
        acc[rb] = __builtin_amdgcn_mfma_f32_16x16x32_bf16(a[rb][ks], bfrag, acc[rb], 0, 0, 0);
    }
    float bv = b4[col];
    float w5 = W5f[col];
#pragma unroll
    for (int rb = 0; rb < 4; rb++) {
#pragma unroll
      for (int r = 0; r < 4; r++) {
        float v = acc[rb][r] + bv;
        v = v >= 0.f ? v : 0.2f * v;  // LeakyReLU(0.2)
        zp[rb][r] += v * w5;
      }
    }
  }

  // butterfly-reduce across the 16 lanes sharing (lane>>4): sums over cols
#pragma unroll
  for (int m = 1; m <= 8; m <<= 1) {
#pragma unroll
    for (int rb = 0; rb < 4; rb++)
#pragma unroll
      for (int r = 0; r < 4; r++) zp[rb][r] += __shfl_xor(zp[rb][r], m);
  }
  if ((lane & 15) == 0) {
    int g4 = lane >> 4;
#pragma unroll
    for (int rb = 0; rb < 4; rb++)
#pragma unroll
      for (int r = 0; r < 4; r++)
        zpartial[wave * 64 + rb * 16 + g4 * 4 + r] = zp[rb][r];
  }
}

template <bool PRE>
__global__ __launch_bounds__(256, 2) void disc_main(
    const float* __restrict__ x, const float* __restrict__ lbl,
    const unsigned short* __restrict__ wb,
    const float* __restrict__ W1f, const float* __restrict__ b1,
    const float* __restrict__ W2f, const float* __restrict__ b2,
    const float* __restrict__ W3f, const float* __restrict__ b3,
    const float* __restrict__ W4f, const float* __restrict__ b4,
    const float* __restrict__ W5f, const float* __restrict__ b5,
    float* __restrict__ out) {
  __shared__ __align__(16) unsigned char bufA[16 * 1024];  // x(4K), h2(16K)
  __shared__ __align__(16) unsigned char bufB[32 * 1024];  // h1(8K), h3(32K)
  __shared__ float zpartial[4 * 64];

  int t = threadIdx.x;
  int wave = t >> 6, lane = t & 63;
  long n0 = (long)blockIdx.x * 64;
  int b = (int)(n0 >> 17);
  int hw0 = (int)(n0 & (HW_ - 1));

  // zero the 4KB x-staging region (covers the k-padding 19->32)
  ((uint4*)bufA)[t] = uint4{0, 0, 0, 0};
  __syncthreads();
  // stage x tile -> bufA as [64 px][32] bf16, swizzle MASK=3
  {
    int px = t & 63;
    for (int c = t >> 6; c < 19; c += 4) {
      float v = x[(((long)b * 19 + c) << 17) + hw0 + px];
      int cb = c * 2;
      int g = (cb >> 4) ^ (px & 3);
      *(unsigned short*)(bufA + px * 64 + (g << 4) + (cb & 15)) = f2bf(v);
    }
  }
  __syncthreads();

  layer_mfma<19, 32, 64, PRE>(wb + OW1, W1f, b1, bufA, bufB, wave, lane);
  __syncthreads();
  layer_mfma<64, 64, 128, PRE>(wb + OW2, W2f, b2, bufB, bufA, wave, lane);
  __syncthreads();
  layer_mfma<128, 128, 256, PRE>(wb + OW3, W3f, b3, bufA, bufB, wave, lane);
  __syncthreads();
  layer4_fused<PRE>(wb + OW4, W4f, b4, W5f, bufB, zpartial, wave, lane);
  __syncthreads();

  // wave 0: combine the 4 wave-partials per pixel, BCE, block reduce
  if (t < 64) {
    float z = zpartial[t] + zpartial[64 + t] + zpartial[128 + t] +
              zpartial[192 + t] + b5[0];
    float l = lbl[n0 + t];
    float w = fmaxf(z, 0.f) - z * l + log1pf(expf(-fabsf(z)));
#pragma unroll
    for (int m = 1; m <= 32; m <<= 1) w += __shfl_xor(w, m);
    if (t == 0) atomicAdd(out, w * (1.f / (float)NPIX));
  }
}

extern "C" void kernel_launch(void* const* d_in, const int* in_sizes, int n_in,
                              void* d_out, int out_size, void* d_ws, size_t ws_size,
                              hipStream_t stream) {
  const float* x   = (const float*)d_in[0];
  const float* lbl = (const float*)d_in[1];
  const float* W1  = (const float*)d_in[2];
  const float* b1  = (const float*)d_in[3];
  const float* W2  = (const float*)d_in[4];
  const float* b2  = (const float*)d_in[5];
  const float* W3  = (const float*)d_in[6];
  const float* b3  = (const float*)d_in[7];
  const float* W4  = (const float*)d_in[8];
  const float* b4  = (const float*)d_in[9];
  const float* W5  = (const float*)d_in[10];
  const float* b5  = (const float*)d_in[11];
  float* out = (float*)d_out;

  hipMemsetAsync(d_out, 0, sizeof(float), stream);

  bool pre = ws_size >= (size_t)WTOT * sizeof(unsigned short);
  if (pre) {
    unsigned short* wbp = (unsigned short*)d_ws;
    wconv_kernel<<<(WTOT + 255) / 256, 256, 0, stream>>>(W1, W2, W3, W4, wbp);
    disc_main<true><<<NPIX / 64, 256, 0, stream>>>(x, lbl, wbp, W1, b1, W2, b2, W3, b3,
                                                   W4, b4, W5, b5, out);
  } else {
    disc_main<false><<<NPIX / 64, 256, 0, stream>>>(x, lbl, nullptr, W1, b1, W2, b2, W3,
                                                    b3, W4, b4, W5, b5, out);
  }
}